// Round 1
// baseline (178.683 us; speedup 1.0000x reference)
//
#include <hip/hip_runtime.h>

typedef __attribute__((ext_vector_type(8))) short          bf16x8;
typedef __attribute__((ext_vector_type(8))) unsigned short u16x8;
typedef __attribute__((ext_vector_type(4))) unsigned short u16x4;
typedef __attribute__((ext_vector_type(4))) float          f32x4;
typedef __attribute__((ext_vector_type(4))) unsigned int   u32x4;

union U8 { u16x8 u; bf16x8 b; u32x4 w; };
union U4 { u16x4 u; unsigned w[2]; };

__device__ __forceinline__ unsigned short f2bf(float f){
  unsigned u = __float_as_uint(f);
  return (unsigned short)((u + 0x7fffu + ((u >> 16) & 1u)) >> 16);
}
// pack two floats to bf16x2 (round-half-up): lo->low16, hi->high16. exact 0 preserved.
__device__ __forceinline__ unsigned pack_bf16(float lo, float hi){
  unsigned a = __float_as_uint(hi) + 0x8000u;
  unsigned b = __float_as_uint(lo) + 0x8000u;
  return __builtin_amdgcn_perm(a, b, 0x07060302u);
}
// max-pair -> packed bf16 (RNE) -> halfword mask. m has 0xFFFF/0x0000 halves.
__device__ __forceinline__ unsigned maskpack(float e0, float e1, unsigned m){
  unsigned r;
  asm("v_cvt_pk_bf16_f32 %0, %1, %2" : "=v"(r) : "v"(e0), "v"(e1));
  return r & m;
}

#define NN  1024
#define FIN 256
#define NH  8
#define FO  64

// ---------------------------------------------------------------------------
// Stage 0: wfrag = w in MFMA-B-frag layout; emask = halfword-expanded A mask
//          (u32 per m-pair: 0xFFFF per live element); out = bias*mz pre-init.
// grid 1024 x 256
// ---------------------------------------------------------------------------
__global__ __launch_bounds__(256) void stage0(
    const float* __restrict__ w, const int* __restrict__ A,
    const float* __restrict__ bias, const float* __restrict__ mz,
    unsigned short* __restrict__ wfrag, unsigned* __restrict__ emask,
    float* __restrict__ out)
{
  const int tid = blockIdx.x * 256 + threadIdx.x;    // 262144 threads
  if (tid < 16384){
    const int lane = tid & 63, ss = (tid >> 6) & 3, kc = (tid >> 8) & 7, h = tid >> 11;
    const int o = 16 * ss + (lane & 15);
    const int f = kc * 32 + (lane >> 4) * 8;
    u16x8 r;
    #pragma unroll
    for (int j = 0; j < 8; j++) r[j] = f2bf(w[(h * FIN + f + j) * FO + o]);
    *(u16x8*)(wfrag + tid * 8) = r;
  }
  #pragma unroll
  for (int k = 0; k < 2; k++){                       // out = bias*mz
    const int i = tid + k * 262144;
    out[i] = bias[i & 63] * mz[i >> 6];
  }
  // adjacency -> expanded halfword masks (8 elems -> 4 u32 per iter)
  const int4* A4 = (const int4*)A;
  for (int i = tid; i < 1048576; i += 262144){
    const int4 a0 = A4[2 * i], a1 = A4[2 * i + 1];
    u32x4 m;
    m[0] = (a0.x > 0 ? 0xFFFFu : 0u) | (a0.y > 0 ? 0xFFFF0000u : 0u);
    m[1] = (a0.z > 0 ? 0xFFFFu : 0u) | (a0.w > 0 ? 0xFFFF0000u : 0u);
    m[2] = (a1.x > 0 ? 0xFFFFu : 0u) | (a1.y > 0 ? 0xFFFF0000u : 0u);
    m[3] = (a1.z > 0 ? 0xFFFFu : 0u) | (a1.w > 0 ? 0xFFFF0000u : 0u);
    *(u32x4*)(emask + 4 * i) = m;
  }
}

// ---------------------------------------------------------------------------
// Stage A: recx built in LDS per 16-row tile; h = recx @ w (MFMA);
// panel stores hT[b,h,mtile,o,32] + exp tables (R = exp(0.8 s), Ed, Ed2).
// grid (64 tiles(16 rows), 8 b) = 512 blocks, block 512 (8 waves = 8 heads).
// ---------------------------------------------------------------------------
__global__ __launch_bounds__(512, 4) void stageA(
    const float* __restrict__ x, const float* __restrict__ e_at,
    const float* __restrict__ Np, const unsigned short* __restrict__ wfrag,
    const float* __restrict__ a_src, const float* __restrict__ a_dst,
    unsigned short* __restrict__ hT,
    float* __restrict__ Rt, float* __restrict__ expd, float* __restrict__ expd2)
{
  __shared__ unsigned short rex[16 * 264];   // 16 rows x 256 f, pad 264
  const int t = threadIdx.x;
  const int n0 = blockIdx.x * 16, b = blockIdx.y;

  {                                          // cooperative recx tile build
    const int row = t >> 5, f0 = (t & 31) * 8;
    const int nrow = n0 + row;
    const float* ep = e_at + (b * NN + nrow) * FIN + f0;
    const float* qp = Np + nrow * FIN + f0;
    const float* xp = x + b * FIN + f0;
    f32x4 e0 = *(const f32x4*)ep, e1 = *(const f32x4*)(ep + 4);
    f32x4 q0 = *(const f32x4*)qp, q1 = *(const f32x4*)(qp + 4);
    f32x4 x0 = *(const f32x4*)xp, x1 = *(const f32x4*)(xp + 4);
    u16x8 r;
    #pragma unroll
    for (int j = 0; j < 4; j++){
      r[j]     = f2bf(e0[j] * q0[j] * x0[j]);
      r[j + 4] = f2bf(e1[j] * q1[j] * x1[j]);
    }
    *(u16x8*)(rex + row * 264 + f0) = r;
  }
  __syncthreads();

  const int h = t >> 6, lane = t & 63, quad = lane >> 4, l15 = lane & 15;
  const unsigned short* wf = wfrag + h * 16384 + lane * 8;

  f32x4 acc[4] = {};
  #pragma unroll
  for (int kc = 0; kc < 8; kc++){
    U8 a0, bf[4];
    a0.u = *(const u16x8*)(rex + l15 * 264 + kc * 32 + quad * 8);
    #pragma unroll
    for (int ss = 0; ss < 4; ss++) bf[ss].u = *(const u16x8*)(wf + (kc * 4 + ss) * 512);
    #pragma unroll
    for (int ss = 0; ss < 4; ss++)
      acc[ss] = __builtin_amdgcn_mfma_f32_16x16x32_bf16(a0.b, bf[ss].b, acc[ss], 0, 0, 0);
  }

  // panel store: [b,h,mtile,o(64),m(32)], C/D row(n)=quad*4+i, col(o)=16ss+l15
  {
    const int mtile = blockIdx.x >> 1, moff = (blockIdx.x & 1) * 16;
    unsigned short* pan = hT + (size_t)(((b * NH + h) * 32 + mtile) * 64) * 32;
    #pragma unroll
    for (int ss = 0; ss < 4; ss++){
      U4 v;
      v.w[0] = pack_bf16(acc[ss][0], acc[ss][1]);
      v.w[1] = pack_bf16(acc[ss][2], acc[ss][3]);
      *(u16x4*)(pan + (16 * ss + l15) * 32 + moff + quad * 4) = v.u;
    }
  }

  // s/d reductions -> exp tables (R = exp(0.8 s): row factor exp(0.2 s) cancels
  // in softmax, so P' = max(R*Ed, Ed2) gives identical attention weights)
  float as4[4], ad4[4];
  #pragma unroll
  for (int ss = 0; ss < 4; ss++){
    as4[ss] = a_src[h * FO + 16 * ss + l15];
    ad4[ss] = a_dst[h * FO + 16 * ss + l15];
  }
  #pragma unroll
  for (int i = 0; i < 4; i++){
    float ps = 0.f, pd = 0.f;
    #pragma unroll
    for (int ss = 0; ss < 4; ss++){ ps += acc[ss][i] * as4[ss]; pd += acc[ss][i] * ad4[ss]; }
    #pragma unroll
    for (int off = 1; off < 16; off <<= 1){
      ps += __shfl_xor(ps, off);
      pd += __shfl_xor(pd, off);
    }
    if (l15 == 0){
      const int idx = (b * NH + h) * NN + n0 + quad * 4 + i;
      Rt[idx]    = __expf(0.8f * ps);
      expd[idx]  = __expf(pd);
      expd2[idx] = __expf(0.2f * pd);
    }
  }
}

// ---------------------------------------------------------------------------
// Stage B: fused masked-softmax aggregation, occupancy-first.
// grid (32 tiles(32 rows), 4 head-pairs, 8 b) = 1024 blocks, block 512
// (8 waves = 2 heads x 2 row-groups x 2 m-halves). 4 blocks/CU = 32 waves/CU.
// P-tile build: 1 mul + 1 max per elem, cvt_pk pack, precomputed-mask AND.
// Row denominators via ones-column MFMA (idle matrix pipe). Head merge via
// global fp32 atomics into pre-initialized out.
// ---------------------------------------------------------------------------
__global__ __launch_bounds__(512, 8) void stageB(
    const unsigned* __restrict__ emask,
    const unsigned short* __restrict__ hT,
    const float* __restrict__ Rt,
    const float* __restrict__ expd, const float* __restrict__ expd2,
    const float* __restrict__ mz, float* __restrict__ out)
{
  __shared__ float ed_l[2 * NN];         // 8 KB (2 heads)
  __shared__ float e2_l[2 * NN];         // 8 KB
  __shared__ float l_l[4 * 16];          // (hl,rg) x 16 rows
  const int t = threadIdx.x;
  const int n0 = blockIdx.x * 32, hq = blockIdx.y, b = blockIdx.z;
  const int w = t >> 6, lane = t & 63, quad = lane >> 4, l15 = lane & 15;
  const int hl = w & 1, rg = (w >> 1) & 1, mh = w >> 2;
  const int h = hq * 2 + hl;

  if (t < 64) l_l[t] = 0.f;
  {                                      // exp-table preload (coalesced)
    const float* s1 = expd  + (b * NH + hq * 2) * NN;
    const float* s2 = expd2 + (b * NH + hq * 2) * NN;
    *(f32x4*)(ed_l + t * 4) = *(const f32x4*)(s1 + t * 4);
    *(f32x4*)(e2_l + t * 4) = *(const f32x4*)(s2 + t * 4);
  }
  __syncthreads();

  const int row = n0 + rg * 16 + l15;
  const float Rv = Rt[(b * NH + h) * NN + row];
  const unsigned short* pb = hT + (size_t)(b * NH + h) * 65536 + l15 * 32 + quad * 8;
  const float* edh = ed_l + hl * NN + quad * 8;
  const float* e2h = e2_l + hl * NN + quad * 8;
  const unsigned* emp = emask + ((size_t)(b * NN) + row) * 512 + quad * 4;
  const int c0 = mh * 16;

  U8 pan[4];
  #pragma unroll
  for (int ss = 0; ss < 4; ss++)
    pan[ss].u = *(const u16x8*)(pb + (size_t)c0 * 2048 + ss * 512);
  u32x4 em = *(const u32x4*)(emp + c0 * 16);

  U8 ones;                               // bf16 1.0 B-frag for row sums
  #pragma unroll
  for (int j = 0; j < 8; j++) ones.u[j] = 0x3F80;

  f32x4 acc[4] = {};
  f32x4 accl = {};

  for (int cc = 0; cc < 16; cc++){
    const int c = c0 + cc;
    f32x4 d01 = *(const f32x4*)(edh + c * 32);
    f32x4 d23 = *(const f32x4*)(edh + c * 32 + 4);
    f32x4 g01 = *(const f32x4*)(e2h + c * 32);
    f32x4 g23 = *(const f32x4*)(e2h + c * 32 + 4);
    f32x4 p01 = Rv * d01, p23 = Rv * d23;
    U8 p;
    p.w[0] = maskpack(fmaxf(p01[0], g01[0]), fmaxf(p01[1], g01[1]), em[0]);
    p.w[1] = maskpack(fmaxf(p01[2], g01[2]), fmaxf(p01[3], g01[3]), em[1]);
    p.w[2] = maskpack(fmaxf(p23[0], g23[0]), fmaxf(p23[1], g23[1]), em[2]);
    p.w[3] = maskpack(fmaxf(p23[2], g23[2]), fmaxf(p23[3], g23[3]), em[3]);
    #pragma unroll
    for (int ss = 0; ss < 4; ss++)
      acc[ss] = __builtin_amdgcn_mfma_f32_16x16x32_bf16(p.b, pan[ss].b, acc[ss], 0, 0, 0);
    accl = __builtin_amdgcn_mfma_f32_16x16x32_bf16(p.b, ones.b, accl, 0, 0, 0);
    if (cc + 1 < 16){
      #pragma unroll
      for (int ss = 0; ss < 4; ss++)
        pan[ss].u = *(const u16x8*)(pb + (size_t)(c + 1) * 2048 + ss * 512);
      em = *(const u32x4*)(emp + (c + 1) * 16);
    }
  }

  // accl[i] = row(quad*4+i) partial denominator (replicated over l15 cols);
  // combine the two m-half waves per (hl,rg)
  if (l15 == 0){
    #pragma unroll
    for (int i = 0; i < 4; i++)
      atomicAdd(&l_l[(w & 3) * 16 + quad * 4 + i], accl[i]);
  }
  __syncthreads();

  // normalize (1/8 folded) * mz, merge heads via global atomics
  const float* mzp = mz + b * NN + n0 + rg * 16;
  #pragma unroll
  for (int i = 0; i < 4; i++){
    const int r = quad * 4 + i;
    const float invm = (0.125f / l_l[(w & 3) * 16 + r]) * mzp[r];
    float* op = out + (size_t)(b * NN + n0 + rg * 16 + r) * FO + l15;
    #pragma unroll
    for (int ss = 0; ss < 4; ss++)
      atomicAdd(op + ss * 16, acc[ss][i] * invm);
  }
}

extern "C" void kernel_launch(void* const* d_in, const int* in_sizes, int n_in,
                              void* d_out, int out_size, void* d_ws, size_t ws_size,
                              hipStream_t stream)
{
  (void)in_sizes; (void)n_in; (void)out_size; (void)ws_size;
  const float* x    = (const float*)d_in[0];
  const int*   A    = (const int*)d_in[1];
  const float* mz   = (const float*)d_in[2];
  const float* e_at = (const float*)d_in[4];
  const float* Np   = (const float*)d_in[5];
  const float* w    = (const float*)d_in[6];
  const float* asrc = (const float*)d_in[7];
  const float* adst = (const float*)d_in[8];
  const float* bias = (const float*)d_in[9];
  float* out = (float*)d_out;

  char* ws = (char*)d_ws;
  unsigned short* wfrag = (unsigned short*)ws;                     // 256 KB
  unsigned short* hT    = (unsigned short*)(ws + 262144);          // 8 MB
  float* Rt    = (float*)(ws + 8650752);                           // 256 KB
  float* expd  = (float*)(ws + 8912896);                           // 256 KB
  float* expd2 = (float*)(ws + 9175040);                           // 256 KB
  unsigned* emask = (unsigned*)(ws + 9437184);                     // 16 MB

  stage0<<<dim3(1024), dim3(256), 0, stream>>>(w, A, bias, mz, wfrag, emask, out);
  stageA<<<dim3(64, 8), dim3(512), 0, stream>>>(x, e_at, Np, wfrag, asrc, adst,
                                                hT, Rt, expd, expd2);
  stageB<<<dim3(32, 4, 8), dim3(512), 0, stream>>>(emask, hT, Rt, expd, expd2,
                                                   mz, out);
}

// Round 2
// 157.987 us; speedup vs baseline: 1.1310x; 1.1310x over previous
//
#include <hip/hip_runtime.h>

typedef __attribute__((ext_vector_type(8))) short          bf16x8;
typedef __attribute__((ext_vector_type(8))) unsigned short u16x8;
typedef __attribute__((ext_vector_type(4))) unsigned short u16x4;
typedef __attribute__((ext_vector_type(4))) float          f32x4;
typedef __attribute__((ext_vector_type(4))) unsigned int   u32x4;

union U8 { u16x8 u; bf16x8 b; u32x4 w; };
union U4 { u16x4 u; unsigned w[2]; };

__device__ __forceinline__ unsigned short f2bf(float f){
  unsigned u = __float_as_uint(f);
  return (unsigned short)((u + 0x7fffu + ((u >> 16) & 1u)) >> 16);
}
// pack two floats to bf16x2 (round-half-up): lo->low16, hi->high16. exact 0 preserved.
__device__ __forceinline__ unsigned pack_bf16(float lo, float hi){
  unsigned a = __float_as_uint(hi) + 0x8000u;
  unsigned b = __float_as_uint(lo) + 0x8000u;
  return __builtin_amdgcn_perm(a, b, 0x07060302u);
}
// max-pair -> packed bf16 (RNE) -> halfword mask (0xFFFF/0x0000 halves).
__device__ __forceinline__ unsigned maskpack(float e0, float e1, unsigned m){
  unsigned r;
  asm("v_cvt_pk_bf16_f32 %0, %1, %2" : "=v"(r) : "v"(e0), "v"(e1));
  return r & m;
}

#define NN  1024
#define FIN 256
#define NH  8
#define FO  64

// ---------------------------------------------------------------------------
// Stage 0: wfrag = w in MFMA-B-frag layout; Abits = bit-packed A;
//          out = bias*mz (pre-init for stageB's atomic head-merge).
// grid 1024 x 256
// ---------------------------------------------------------------------------
__global__ __launch_bounds__(256) void stage0(
    const float* __restrict__ w, const int* __restrict__ A,
    const float* __restrict__ bias, const float* __restrict__ mz,
    unsigned short* __restrict__ wfrag, unsigned long long* __restrict__ Abits,
    float* __restrict__ out)
{
  const int tid = blockIdx.x * 256 + threadIdx.x;    // 262144 threads
  if (tid < 16384){
    const int lane = tid & 63, ss = (tid >> 6) & 3, kc = (tid >> 8) & 7, h = tid >> 11;
    const int o = 16 * ss + (lane & 15);
    const int f = kc * 32 + (lane >> 4) * 8;
    u16x8 r;
    #pragma unroll
    for (int j = 0; j < 8; j++) r[j] = f2bf(w[(h * FIN + f + j) * FO + o]);
    *(u16x8*)(wfrag + tid * 8) = r;
  }
  #pragma unroll
  for (int k = 0; k < 2; k++){                       // out = bias*mz
    const int i = tid + k * 262144;
    out[i] = bias[i & 63] * mz[i >> 6];
  }
  for (int i = tid; i < 8388608; i += 262144){       // adjacency bit-pack
    unsigned long long m = __ballot(A[i] > 0);
    if ((threadIdx.x & 63) == 0) Abits[i >> 6] = m;
  }
}

// ---------------------------------------------------------------------------
// Stage A: recx built in LDS per 16-row tile; h = recx @ w (MFMA);
// panel stores hT[b,h,mtile,o,32] + exp tables (R = exp(0.8 s), Ed, Ed2).
// grid (64 tiles(16 rows), 8 b) = 512 blocks, block 512 (8 waves = 8 heads).
// ---------------------------------------------------------------------------
__global__ __launch_bounds__(512, 4) void stageA(
    const float* __restrict__ x, const float* __restrict__ e_at,
    const float* __restrict__ Np, const unsigned short* __restrict__ wfrag,
    const float* __restrict__ a_src, const float* __restrict__ a_dst,
    unsigned short* __restrict__ hT,
    float* __restrict__ Rt, float* __restrict__ expd, float* __restrict__ expd2)
{
  __shared__ unsigned short rex[16 * 264];   // 16 rows x 256 f, pad 264
  const int t = threadIdx.x;
  const int n0 = blockIdx.x * 16, b = blockIdx.y;

  {                                          // cooperative recx tile build
    const int row = t >> 5, f0 = (t & 31) * 8;
    const int nrow = n0 + row;
    const float* ep = e_at + (b * NN + nrow) * FIN + f0;
    const float* qp = Np + nrow * FIN + f0;
    const float* xp = x + b * FIN + f0;
    f32x4 e0 = *(const f32x4*)ep, e1 = *(const f32x4*)(ep + 4);
    f32x4 q0 = *(const f32x4*)qp, q1 = *(const f32x4*)(qp + 4);
    f32x4 x0 = *(const f32x4*)xp, x1 = *(const f32x4*)(xp + 4);
    u16x8 r;
    #pragma unroll
    for (int j = 0; j < 4; j++){
      r[j]     = f2bf(e0[j] * q0[j] * x0[j]);
      r[j + 4] = f2bf(e1[j] * q1[j] * x1[j]);
    }
    *(u16x8*)(rex + row * 264 + f0) = r;
  }
  __syncthreads();

  const int h = t >> 6, lane = t & 63, quad = lane >> 4, l15 = lane & 15;
  const unsigned short* wf = wfrag + h * 16384 + lane * 8;

  f32x4 acc[4] = {};
  #pragma unroll
  for (int kc = 0; kc < 8; kc++){
    U8 a0, bf[4];
    a0.u = *(const u16x8*)(rex + l15 * 264 + kc * 32 + quad * 8);
    #pragma unroll
    for (int ss = 0; ss < 4; ss++) bf[ss].u = *(const u16x8*)(wf + (kc * 4 + ss) * 512);
    #pragma unroll
    for (int ss = 0; ss < 4; ss++)
      acc[ss] = __builtin_amdgcn_mfma_f32_16x16x32_bf16(a0.b, bf[ss].b, acc[ss], 0, 0, 0);
  }

  // panel store: [b,h,mtile,o(64),m(32)], C/D row(n)=quad*4+i, col(o)=16ss+l15
  {
    const int mtile = blockIdx.x >> 1, moff = (blockIdx.x & 1) * 16;
    unsigned short* pan = hT + (size_t)(((b * NH + h) * 32 + mtile) * 64) * 32;
    #pragma unroll
    for (int ss = 0; ss < 4; ss++){
      U4 v;
      v.w[0] = pack_bf16(acc[ss][0], acc[ss][1]);
      v.w[1] = pack_bf16(acc[ss][2], acc[ss][3]);
      *(u16x4*)(pan + (16 * ss + l15) * 32 + moff + quad * 4) = v.u;
    }
  }

  // s/d reductions -> exp tables (R = exp(0.8 s): row factor exp(0.2 s) cancels
  // in softmax, so P' = max(R*Ed, Ed2) gives identical attention weights)
  float as4[4], ad4[4];
  #pragma unroll
  for (int ss = 0; ss < 4; ss++){
    as4[ss] = a_src[h * FO + 16 * ss + l15];
    ad4[ss] = a_dst[h * FO + 16 * ss + l15];
  }
  #pragma unroll
  for (int i = 0; i < 4; i++){
    float ps = 0.f, pd = 0.f;
    #pragma unroll
    for (int ss = 0; ss < 4; ss++){ ps += acc[ss][i] * as4[ss]; pd += acc[ss][i] * ad4[ss]; }
    #pragma unroll
    for (int off = 1; off < 16; off <<= 1){
      ps += __shfl_xor(ps, off);
      pd += __shfl_xor(pd, off);
    }
    if (l15 == 0){
      const int idx = (b * NH + h) * NN + n0 + quad * 4 + i;
      Rt[idx]    = __expf(0.8f * ps);
      expd[idx]  = __expf(pd);
      expd2[idx] = __expf(0.2f * pd);
    }
  }
}

// ---------------------------------------------------------------------------
// Stage B: fused masked-softmax aggregation.
// 1024 flat blocks of 256 thr (4 waves = 2 heads x 2 m-halves); each wave owns
// 32 rows (both row-groups) x 512 cols -> every pan B-frag feeds 2 MFMAs
// (panel L2 traffic halved vs 1-rg waves). Block decode is XCD-grouped so the
// 32 blocks sharing a (b,hq) panel land on one XCD: 4 panels x 256KB = 1MB
// working set per XCD L2 -> panel reuse served by L2, not L3.
// Mask: bit-packed Abits in LDS + 16-entry LUT expand (no global mask reads).
// Row denominators via ones-column MFMA. Head merge via global fp32 atomics.
// ---------------------------------------------------------------------------
__global__ __launch_bounds__(256, 4) void stageB(
    const unsigned* __restrict__ Aw,
    const unsigned short* __restrict__ hT,
    const float* __restrict__ Rt,
    const float* __restrict__ expd, const float* __restrict__ expd2,
    const float* __restrict__ mz, float* __restrict__ out)
{
  __shared__ float ed_l[2 * NN];                 // 8 KB (2 heads)
  __shared__ float e2_l[2 * NN];                 // 8 KB
  __shared__ unsigned mask_l[32 * 33];           // 4.2 KB, pad 33 vs bank stride
  __shared__ __align__(8) unsigned lut[16][2];   // nibble -> 2 halfword masks
  __shared__ float l_l[4 * 16];                  // (hl,rg) x 16 rows

  // XCD-grouped swizzle: dispatch rr assigns blockIdx.x%8 -> XCD; give each
  // XCD a contiguous 128-block chunk = 4 (b,hq) panel groups.
  const int fid = blockIdx.x;
  const int gb = (fid & 7) * 128 + (fid >> 3);
  const int n0 = (gb & 31) * 32, hq = (gb >> 5) & 3, b = gb >> 7;

  const int t = threadIdx.x;                     // 256
  const int w = t >> 6, lane = t & 63, quad = lane >> 4, l15 = lane & 15;
  const int hl = w & 1, mh = w >> 1;
  const int h = hq * 2 + hl;

  if (t < 64) l_l[t] = 0.f;
  if (t < 16){
    lut[t][0] = (t & 1 ? 0xFFFFu : 0u) | (t & 2 ? 0xFFFF0000u : 0u);
    lut[t][1] = (t & 4 ? 0xFFFFu : 0u) | (t & 8 ? 0xFFFF0000u : 0u);
  }
  {                                      // exp-table preload (coalesced)
    const float* s1 = expd  + (b * NH + hq * 2) * NN;
    const float* s2 = expd2 + (b * NH + hq * 2) * NN;
    *(f32x4*)(ed_l + t * 8)     = *(const f32x4*)(s1 + t * 8);
    *(f32x4*)(ed_l + t * 8 + 4) = *(const f32x4*)(s1 + t * 8 + 4);
    *(f32x4*)(e2_l + t * 8)     = *(const f32x4*)(s2 + t * 8);
    *(f32x4*)(e2_l + t * 8 + 4) = *(const f32x4*)(s2 + t * 8 + 4);
  }
  #pragma unroll
  for (int k = 0; k < 4; k++){           // bit-mask preload: 32 rows x 32 u32
    const int i = t + k * 256;
    mask_l[(i >> 5) * 33 + (i & 31)] = Aw[(b * NN + n0 + (i >> 5)) * 32 + (i & 31)];
  }
  __syncthreads();

  const int hb = (b * NH + h) * NN;
  const float Rv0 = Rt[hb + n0 + l15];
  const float Rv1 = Rt[hb + n0 + 16 + l15];
  const unsigned short* pb = hT + (size_t)(b * NH + h) * 65536 + l15 * 32 + quad * 8;
  const float* edh = ed_l + hl * NN + quad * 8;
  const float* e2h = e2_l + hl * NN + quad * 8;
  const int c0 = mh * 16;
  const int qs = quad * 8;

  U8 pan[4];
  #pragma unroll
  for (int ss = 0; ss < 4; ss++)
    pan[ss].u = *(const u16x8*)(pb + (size_t)c0 * 2048 + ss * 512);
  unsigned mw0 = mask_l[l15 * 33 + c0];
  unsigned mw1 = mask_l[(16 + l15) * 33 + c0];

  U8 ones;                               // bf16 1.0 B-frag for row sums
  #pragma unroll
  for (int j = 0; j < 8; j++) ones.u[j] = 0x3F80;

  f32x4 acc0[4] = {}, acc1[4] = {};
  f32x4 accl0 = {}, accl1 = {};

  for (int cc = 0; cc < 16; cc++){
    const int c = c0 + cc;
    // expand bit masks via LUT (mask words prefetched last iter -> LDS reads
    // issue at iter top, latency overlapped with edh loads + muls)
    const unsigned am0 = (mw0 >> qs) & 0xFF;
    const unsigned am1 = (mw1 >> qs) & 0xFF;
    const uint2 la0 = *(const uint2*)&lut[am0 & 15][0];
    const uint2 lb0 = *(const uint2*)&lut[(am0 >> 4) & 15][0];
    const uint2 la1 = *(const uint2*)&lut[am1 & 15][0];
    const uint2 lb1 = *(const uint2*)&lut[(am1 >> 4) & 15][0];
    if (cc + 1 < 16){
      mw0 = mask_l[l15 * 33 + c + 1];
      mw1 = mask_l[(16 + l15) * 33 + c + 1];
    }
    // shared column factors (broadcast LDS reads, conflict-free)
    const f32x4 d01 = *(const f32x4*)(edh + c * 32);
    const f32x4 d23 = *(const f32x4*)(edh + c * 32 + 4);
    const f32x4 g01 = *(const f32x4*)(e2h + c * 32);
    const f32x4 g23 = *(const f32x4*)(e2h + c * 32 + 4);
    // P for row-group 0
    {
      const f32x4 p01 = Rv0 * d01, p23 = Rv0 * d23;
      U8 p;
      p.w[0] = maskpack(fmaxf(p01[0], g01[0]), fmaxf(p01[1], g01[1]), la0.x);
      p.w[1] = maskpack(fmaxf(p01[2], g01[2]), fmaxf(p01[3], g01[3]), la0.y);
      p.w[2] = maskpack(fmaxf(p23[0], g23[0]), fmaxf(p23[1], g23[1]), lb0.x);
      p.w[3] = maskpack(fmaxf(p23[2], g23[2]), fmaxf(p23[3], g23[3]), lb0.y);
      #pragma unroll
      for (int ss = 0; ss < 4; ss++)
        acc0[ss] = __builtin_amdgcn_mfma_f32_16x16x32_bf16(p.b, pan[ss].b, acc0[ss], 0, 0, 0);
      accl0 = __builtin_amdgcn_mfma_f32_16x16x32_bf16(p.b, ones.b, accl0, 0, 0, 0);
    }
    // P for row-group 1 (same pan frags -> panel traffic halved)
    {
      const f32x4 p01 = Rv1 * d01, p23 = Rv1 * d23;
      U8 p;
      p.w[0] = maskpack(fmaxf(p01[0], g01[0]), fmaxf(p01[1], g01[1]), la1.x);
      p.w[1] = maskpack(fmaxf(p01[2], g01[2]), fmaxf(p01[3], g01[3]), la1.y);
      p.w[2] = maskpack(fmaxf(p23[0], g23[0]), fmaxf(p23[1], g23[1]), lb1.x);
      p.w[3] = maskpack(fmaxf(p23[2], g23[2]), fmaxf(p23[3], g23[3]), lb1.y);
      #pragma unroll
      for (int ss = 0; ss < 4; ss++)
        acc1[ss] = __builtin_amdgcn_mfma_f32_16x16x32_bf16(p.b, pan[ss].b, acc1[ss], 0, 0, 0);
      accl1 = __builtin_amdgcn_mfma_f32_16x16x32_bf16(p.b, ones.b, accl1, 0, 0, 0);
    }
    if (cc + 1 < 16){                    // pan prefetch, 1-deep (back of chain)
      #pragma unroll
      for (int ss = 0; ss < 4; ss++)
        pan[ss].u = *(const u16x8*)(pb + (size_t)(c + 1) * 2048 + ss * 512);
    }
  }

  // accl[i] = row(quad*4+i) partial denominator (replicated over l15 cols);
  // combine the two m-half waves per (hl,rg)
  if (l15 == 0){
    #pragma unroll
    for (int i = 0; i < 4; i++){
      atomicAdd(&l_l[(hl * 2 + 0) * 16 + quad * 4 + i], accl0[i]);
      atomicAdd(&l_l[(hl * 2 + 1) * 16 + quad * 4 + i], accl1[i]);
    }
  }
  __syncthreads();

  // normalize (1/8 folded) * mz, merge heads via global atomics
  const float* mzp = mz + b * NN + n0;
  #pragma unroll
  for (int i = 0; i < 4; i++){
    const int r16 = quad * 4 + i;
    const float invm0 = (0.125f / l_l[(hl * 2 + 0) * 16 + r16]) * mzp[r16];
    const float invm1 = (0.125f / l_l[(hl * 2 + 1) * 16 + r16]) * mzp[16 + r16];
    float* op0 = out + (size_t)(b * NN + n0 + r16) * FO + l15;
    float* op1 = out + (size_t)(b * NN + n0 + 16 + r16) * FO + l15;
    #pragma unroll
    for (int ss = 0; ss < 4; ss++){
      atomicAdd(op0 + ss * 16, acc0[ss][i] * invm0);
      atomicAdd(op1 + ss * 16, acc1[ss][i] * invm1);
    }
  }
}

extern "C" void kernel_launch(void* const* d_in, const int* in_sizes, int n_in,
                              void* d_out, int out_size, void* d_ws, size_t ws_size,
                              hipStream_t stream)
{
  (void)in_sizes; (void)n_in; (void)out_size; (void)ws_size;
  const float* x    = (const float*)d_in[0];
  const int*   A    = (const int*)d_in[1];
  const float* mz   = (const float*)d_in[2];
  const float* e_at = (const float*)d_in[4];
  const float* Np   = (const float*)d_in[5];
  const float* w    = (const float*)d_in[6];
  const float* asrc = (const float*)d_in[7];
  const float* adst = (const float*)d_in[8];
  const float* bias = (const float*)d_in[9];
  float* out = (float*)d_out;

  char* ws = (char*)d_ws;
  unsigned short* wfrag = (unsigned short*)ws;                     // 256 KB
  unsigned short* hT    = (unsigned short*)(ws + 262144);          // 8 MB
  float* Rt    = (float*)(ws + 8650752);                           // 256 KB
  float* expd  = (float*)(ws + 8912896);                           // 256 KB
  float* expd2 = (float*)(ws + 9175040);                           // 256 KB
  unsigned long long* Abits = (unsigned long long*)(ws + 9437184); // 1 MB

  stage0<<<dim3(1024), dim3(256), 0, stream>>>(w, A, bias, mz, wfrag, Abits, out);
  stageA<<<dim3(64, 8), dim3(512), 0, stream>>>(x, e_at, Np, wfrag, asrc, adst,
                                                hT, Rt, expd, expd2);
  stageB<<<dim3(1024), dim3(256), 0, stream>>>((const unsigned*)Abits, hT,
                                               Rt, expd, expd2, mz, out);
}